// Round 1
// baseline (616.486 us; speedup 1.0000x reference)
//
#include <hip/hip_runtime.h>

// Conv2DProduct: one-hot "sparse product" conv in log space.
// out[b,i,j,o] = x[b,2i,2j, o&31] + x[b,2i,2j+1, (o>>5)&15]
//             + x[b,2i+1,2j, 0]   + x[b,2i+1,2j+1, 0]
// Shapes: x [64,128,128,32] f32, out [64,64,64,512] f32.
// The one-hot kernel input (d_in[1]) is mathematically redundant — ignored.
//
// Structure (R1): grid-stride, each work-item u = pix*64 + o4h computes TWO
// output float4s (channels [4*o4h..4*o4h+3] and [256+4*o4h..259+4*o4h]) of
// pixel pix, sharing one float4 'a' load (since (o+256)&31 == o&31).
// One wave == one pixel (pix = u>>6 wave-uniform), so the row-1 scalar loads
// are hardware-broadcast. 8192 blocks instead of 131,072.

constexpr int B     = 64;
constexpr int H     = 128;
constexpr int W     = 128;
constexpr int C_IN  = 32;
constexpr int HO    = 64;
constexpr int WO    = 64;
constexpr int C_OUT = 512;

constexpr int NPIX    = B * HO * WO;          // 262,144 output pixels
constexpr int TOTAL_U = NPIX * 64;            // work-items (each -> 2 float4) = 16,777,216
constexpr int BLOCK   = 256;
constexpr int GRID    = 8192;
constexpr int STRIDE  = BLOCK * GRID;         // 2,097,152 threads
constexpr int ITERS   = TOTAL_U / STRIDE;     // 8 (exact)

static_assert(TOTAL_U % STRIDE == 0, "exact grid-stride");

__global__ __launch_bounds__(BLOCK) void conv2d_product_kernel(
    const float* __restrict__ x, float* __restrict__ out) {
    const int t = blockIdx.x * BLOCK + threadIdx.x;

#pragma unroll
    for (int k = 0; k < ITERS; ++k) {
        const int u   = t + k * STRIDE;
        const int o4h = u & 63;       // lane id; half-index into 128 float4s/pixel
        const int pix = u >> 6;       // b*HO*WO + i*WO + j  (wave-uniform)

        // x offset of input pixel (2i, 2j) in floats:
        //   b*524288 + i*8192 + j*64 == (pix + (pix & ~63)) << 6
        const int xoff = (pix + (pix & ~63)) << 6;
        const float* xb = x + xoff;

        // cell (0,0): 4 consecutive channels, shared by both output halves
        const float4 a = *(const float4*)(xb + ((o4h & 7) << 2));

        // cell (0,1): channel (o>>5) for each half
        const int bi = C_IN + (o4h >> 3);
        const float b0 = xb[bi];          // half 0: channels (o>>5) in 0..7
        const float b1 = xb[bi + 8];      // half 1: channels 8..15

        // cells (1,0),(1,1): channel 0 of next row (wave-uniform broadcast)
        const float s = xb[W * C_IN] + xb[W * C_IN + C_IN];

        const float add0 = b0 + s;
        const float add1 = b1 + s;

        float4 r0, r1;
        r0.x = a.x + add0; r0.y = a.y + add0; r0.z = a.z + add0; r0.w = a.w + add0;
        r1.x = a.x + add1; r1.y = a.y + add1; r1.z = a.z + add1; r1.w = a.w + add1;

        float4* op = (float4*)out + (((size_t)pix) << 7) + o4h;
        op[0]  = r0;   // float4 index pix*128 + o4h
        op[64] = r1;   // float4 index pix*128 + o4h + 64
    }
}

extern "C" void kernel_launch(void* const* d_in, const int* in_sizes, int n_in,
                              void* d_out, int out_size, void* d_ws, size_t ws_size,
                              hipStream_t stream) {
    const float* x = (const float*)d_in[0];
    float* out = (float*)d_out;
    conv2d_product_kernel<<<GRID, BLOCK, 0, stream>>>(x, out);
}